// Round 2
// baseline (224.829 us; speedup 1.0000x reference)
//
#include <hip/hip_runtime.h>
#include <math.h>

// SNN event model: causal conv (K=8) + LIF scan + outputs (I, z, s, logits).
// Layout: x (32,1,8192) f32, conv_w (64,1,8) f32, raw_tau (64,) f32.
// out = [I (32*64*8192), z (same), s (same), logits (32*8192)] fp32.
//
// Parallelization: time split into NCH chunks per (b) with warm-up W; each
// block = 1 wave (64 lanes = 64 features) handles one (b, chunk).
// fp64 recurrence (compute is free; we are write-BW bound at ~202 MB).
//
// R1: removed __syncthreads (no effect — backend already elides barriers for
//     single-wave workgroups; R0 == R1 codegen).
// R2: occupancy push. Old grid = 2048 blocks = 8/CU (LDS-capped) = 2
//     waves/SIMD; VALU/DS/store phases can't overlap -> latency-bound at
//     ~2.3 TB/s effective write BW. Now CHUNK=64 (4096 blocks) + TS=16
//     (LDS 18.75 KB -> 9.8 KB) -> 16 WGs/CU = 4 waves/SIMD, all resident.
//     Warm-up fraction rises (96/160 vs 96/224) — deliberate trade.
//     Logits reduction made wave-parallel (4 groups x 16 times + shfl_xor).

#define LL 8192
#define BB 32
#define FF 64
#define KK 8
#define CHUNK 64
#define NCH 128             // LL / CHUNK
#define WARM 96
#define NX (WARM + 7 + CHUNK)  // 167
#define TS 16               // flush tile (timesteps buffered in LDS)
#define NT (CHUNK / TS)     // 4

__global__ __launch_bounds__(64) void snn_kernel(
    const float* __restrict__ x, const float* __restrict__ conv_w,
    const float* __restrict__ raw_tau, float* __restrict__ out)
{
    __shared__ double x_lds[NX + 1];        // 1344 B
    __shared__ float I_tile[FF][TS + 1];    // 4352 B, stride 17 (odd): 2-way max
    __shared__ float z_tile[FF][TS + 1];    // 4352 B   -> total 10048 B < 10240

    const int f  = threadIdx.x;            // lane = feature
    const int b  = blockIdx.y;
    const int c  = blockIdx.x;
    const int t0 = c * CHUNK;
    const int g0 = t0 - WARM - 7;          // global time of x_lds[0]

    // ---- per-feature weights: unit-norm filter + alpha ----
    double wd[KK];
    double ss = 0.0;
    #pragma unroll
    for (int k = 0; k < KK; ++k) {
        double wv = (double)conv_w[f * KK + k];
        wd[k] = wv;
        ss += wv * wv;
    }
    double nrm = sqrt(ss);
    if (nrm < 1e-8) nrm = 1e-8;
    double invn = 1.0 / nrm;
    #pragma unroll
    for (int k = 0; k < KK; ++k) wd[k] *= invn;

    double rt    = (double)raw_tau[f];
    double tau   = log1p(exp(rt)) + 1e-4;  // softplus + eps
    double alpha = exp(-1.0 / tau);
    double oma   = 1.0 - alpha;

    // ---- stage 20*x into LDS (zero pad for t<0) ----
    for (int i = f; i < NX; i += 64) {
        int g = g0 + i;
        x_lds[i] = (g >= 0) ? (double)(20.0f * x[(size_t)b * LL + g]) : 0.0;
    }
    // single-wave block: in-order DS pipe makes barriers unnecessary.

    float* outI  = out;
    float* outZ  = out + (size_t)BB * FF * LL;
    float* outS  = out + (size_t)2 * BB * FF * LL;
    float* outLg = out + (size_t)3 * BB * FF * LL;

    double v = 0.0;

    // ---- warm-up (chunk 0: x is all zero-pad early, v stays 0 — harmless) ----
    #pragma unroll 8
    for (int s = 0; s < WARM; ++s) {
        double acc = 0.0;
        #pragma unroll
        for (int k = 0; k < KK; ++k) acc = fma(wd[k], x_lds[s + k], acc);
        double vp = fma(alpha, v, oma * acc);
        v = (vp >= 0.25) ? 0.0 : vp;
    }

    // ---- main chunk: compute + tile in LDS, flush coalesced ----
    for (int tile = 0; tile < NT; ++tile) {
        #pragma unroll
        for (int j = 0; j < TS; ++j) {
            int s = WARM + tile * TS + j;
            double acc = 0.0;
            #pragma unroll
            for (int k = 0; k < KK; ++k) acc = fma(wd[k], x_lds[s + k], acc);
            double vp = fma(alpha, v, oma * acc);
            double z  = 15.0 * (vp - 0.25);
            I_tile[f][j] = (float)acc;
            z_tile[f][j] = (float)z;
            v = (vp >= 0.25) ? 0.0 : vp;
        }

        const int gt = t0 + tile * TS;
        {
            // 64 lanes -> 16 rows x 4 float4-columns per iteration (1 KB/instr,
            // 64-B aligned full-line segments); coalesced stores.
            int r = f >> 2;          // row within group (0..15)
            int q = (f & 3) * 4;     // time offset (16B aligned)
            #pragma unroll
            for (int it = 0; it < NT; ++it) {
                int fr = it * 16 + r;
                size_t base = ((size_t)b * FF + fr) * LL + gt + q;
                float4 vi = make_float4(I_tile[fr][q], I_tile[fr][q + 1],
                                        I_tile[fr][q + 2], I_tile[fr][q + 3]);
                float4 vz = make_float4(z_tile[fr][q], z_tile[fr][q + 1],
                                        z_tile[fr][q + 2], z_tile[fr][q + 3]);
                float4 vs = make_float4(vz.x >= 0.f ? 1.f : 0.f,
                                        vz.y >= 0.f ? 1.f : 0.f,
                                        vz.z >= 0.f ? 1.f : 0.f,
                                        vz.w >= 0.f ? 1.f : 0.f);
                *reinterpret_cast<float4*>(outI + base) = vi;
                *reinterpret_cast<float4*>(outZ + base) = vz;
                *reinterpret_cast<float4*>(outS + base) = vs;
            }
            // logits: wave-parallel max over features. lane = t + 16*g:
            // each lane reduces 16 features at time gt+t, then xor-combine.
            int t = f & 15, g = f >> 4;
            float m = z_tile[g * 16][t];
            #pragma unroll
            for (int i = 1; i < 16; ++i) m = fmaxf(m, z_tile[g * 16 + i][t]);
            m = fmaxf(m, __shfl_xor(m, 16));
            m = fmaxf(m, __shfl_xor(m, 32));
            if (f < 16) outLg[(size_t)b * LL + gt + f] = m;
        }
    }
}

extern "C" void kernel_launch(void* const* d_in, const int* in_sizes, int n_in,
                              void* d_out, int out_size, void* d_ws, size_t ws_size,
                              hipStream_t stream) {
    const float* x  = (const float*)d_in[0];
    const float* w  = (const float*)d_in[1];
    const float* rt = (const float*)d_in[2];
    float* out = (float*)d_out;
    dim3 grid(NCH, BB);
    snn_kernel<<<grid, 64, 0, stream>>>(x, w, rt, out);
}

// Round 4
// 215.623 us; speedup vs baseline: 1.0427x; 1.0427x over previous
//
#include <hip/hip_runtime.h>
#include <math.h>

// SNN event model: causal conv (K=8) + LIF scan + outputs (I, z, s, logits).
// Layout: x (32,1,8192) f32, conv_w (64,1,8) f32, raw_tau (64,) f32.
// out = [I (32*64*8192), z (same), s (same), logits (32*8192)] fp32.
//
// Parallelization: time split into NCH chunks per (b) with warm-up W; each
// block = 1 wave (64 lanes = 64 features) handles one (b, chunk).
//
// R1: removed __syncthreads (no effect — backend elides barriers for
//     single-wave workgroups).
// R2: CHUNK=64/TS=16 occupancy push -> REGRESSED (+18 us). Time tracks total
//     scan-step count; not latency-bound. Reverted.
// R3: fp32 datapath + nontemporal stores. Compile error: builtin needs a
//     clang vector type, not HIP_vector_type. R4 = same kernel with
//     ext_vector_type(4) for the NT stores.

#define LL 8192
#define BB 32
#define FF 64
#define KK 8
#define CHUNK 128
#define NCH 64              // LL / CHUNK
#define WARM 96
#define NX (WARM + 7 + CHUNK)  // 231
#define TS 32               // flush tile (timesteps buffered in LDS)
#define NT (CHUNK / TS)     // 4

typedef float f32x4 __attribute__((ext_vector_type(4)));

__global__ __launch_bounds__(64) void snn_kernel(
    const float* __restrict__ x, const float* __restrict__ conv_w,
    const float* __restrict__ raw_tau, float* __restrict__ out)
{
    __shared__ float x_lds[NX + 1];        // 928 B
    __shared__ float I_tile[FF][TS + 1];   // 8448 B, stride 33: conflict-free cols
    __shared__ float z_tile[FF][TS + 1];   // 8448 B

    const int f  = threadIdx.x;            // lane = feature
    const int b  = blockIdx.y;
    const int c  = blockIdx.x;
    const int t0 = c * CHUNK;
    const int g0 = t0 - WARM - 7;          // global time of x_lds[0]

    // ---- per-feature weights: unit-norm filter + alpha (fp64 setup, f32 use) ----
    double wdd[KK];
    double ss = 0.0;
    #pragma unroll
    for (int k = 0; k < KK; ++k) {
        double wv = (double)conv_w[f * KK + k];
        wdd[k] = wv;
        ss += wv * wv;
    }
    double nrm = sqrt(ss);
    if (nrm < 1e-8) nrm = 1e-8;
    double invn = 1.0 / nrm;
    float wf[KK];
    #pragma unroll
    for (int k = 0; k < KK; ++k) wf[k] = (float)(wdd[k] * invn);

    double rt     = (double)raw_tau[f];
    double tau    = log1p(exp(rt)) + 1e-4;  // softplus + eps
    double alphad = exp(-1.0 / tau);
    float alpha = (float)alphad;
    float oma   = (float)(1.0 - alphad);

    // ---- stage 20*x into LDS (zero pad for t<0) ----
    for (int i = f; i < NX; i += 64) {
        int g = g0 + i;
        x_lds[i] = (g >= 0) ? (20.0f * x[(size_t)b * LL + g]) : 0.0f;
    }
    // single-wave block: in-order DS pipe, no barrier needed.

    float* outI  = out;
    float* outZ  = out + (size_t)BB * FF * LL;
    float* outS  = out + (size_t)2 * BB * FF * LL;
    float* outLg = out + (size_t)3 * BB * FF * LL;

    float v = 0.0f;

    // ---- warm-up (chunk 0: x is all zero-pad early, v stays 0 — harmless) ----
    #pragma unroll 8
    for (int s = 0; s < WARM; ++s) {
        float acc = 0.0f;
        #pragma unroll
        for (int k = 0; k < KK; ++k) acc = fmaf(wf[k], x_lds[s + k], acc);
        float vp = fmaf(alpha, v, oma * acc);
        v = (vp >= 0.25f) ? 0.0f : vp;
    }

    // ---- main chunk: compute + tile in LDS, flush coalesced ----
    for (int tile = 0; tile < NT; ++tile) {
        #pragma unroll
        for (int j = 0; j < TS; ++j) {
            int s = WARM + tile * TS + j;
            float acc = 0.0f;
            #pragma unroll
            for (int k = 0; k < KK; ++k) acc = fmaf(wf[k], x_lds[s + k], acc);
            float vp = fmaf(alpha, v, oma * acc);
            float z  = fmaf(15.0f, vp, -3.75f);   // 15*(vp-0.25)
            I_tile[f][j] = acc;
            z_tile[f][j] = z;
            v = (vp >= 0.25f) ? 0.0f : vp;
        }

        const int gt = t0 + tile * TS;
        {
            // 64 lanes -> 8 rows x 8 float4-columns per iteration: each row gets
            // a full 128-B line per instruction; coalesced stores.
            int r = f >> 3;          // row within group (0..7)
            int q = (f & 7) * 4;     // time offset (16B aligned)
            #pragma unroll
            for (int it = 0; it < 8; ++it) {
                int fr = it * 8 + r;
                size_t base = ((size_t)b * FF + fr) * LL + gt + q;
                f32x4 vi = { I_tile[fr][q], I_tile[fr][q + 1],
                             I_tile[fr][q + 2], I_tile[fr][q + 3] };
                f32x4 vz = { z_tile[fr][q], z_tile[fr][q + 1],
                             z_tile[fr][q + 2], z_tile[fr][q + 3] };
                f32x4 vs = { vz.x >= 0.f ? 1.f : 0.f,
                             vz.y >= 0.f ? 1.f : 0.f,
                             vz.z >= 0.f ? 1.f : 0.f,
                             vz.w >= 0.f ? 1.f : 0.f };
                __builtin_nontemporal_store(vi, reinterpret_cast<f32x4*>(outI + base));
                __builtin_nontemporal_store(vz, reinterpret_cast<f32x4*>(outZ + base));
                __builtin_nontemporal_store(vs, reinterpret_cast<f32x4*>(outS + base));
            }
            // logits: wave-parallel max over features. lane = t + 32*g: each
            // lane reduces 32 features at time gt+t, then one xor-combine.
            int t = f & 31, g = f >> 5;
            float m = z_tile[g * 32][t];
            #pragma unroll
            for (int i = 1; i < 32; ++i) m = fmaxf(m, z_tile[g * 32 + i][t]);
            m = fmaxf(m, __shfl_xor(m, 32));
            if (f < 32) outLg[(size_t)b * LL + gt + f] = m;
        }
    }
}

extern "C" void kernel_launch(void* const* d_in, const int* in_sizes, int n_in,
                              void* d_out, int out_size, void* d_ws, size_t ws_size,
                              hipStream_t stream) {
    const float* x  = (const float*)d_in[0];
    const float* w  = (const float*)d_in[1];
    const float* rt = (const float*)d_in[2];
    float* out = (float*)d_out;
    dim3 grid(NCH, BB);
    snn_kernel<<<grid, 64, 0, stream>>>(x, w, rt, out);
}